// Round 17
// baseline (72.590 us; speedup 1.0000x reference)
//
#include <hip/hip_runtime.h>
#include <hip/hip_bf16.h>
#include <math.h>

#define VOCAB 2048
#define EMB 256
#define MAXLEN 8
#define NBATCH 16
#define LAT 16

typedef unsigned short u16;
typedef unsigned int u32;
using bf16x8 = __attribute__((ext_vector_type(8))) short;
using f32x4  = __attribute__((ext_vector_type(4))) float;

// token = argmax_j ( j/2048 <= v && v <= (j+1)/2048 ), 0 if none.
// cumsum of uniform softmax is exactly k/2048 in fp32; v*2048 is exact.
__device__ __forceinline__ int token_of(float v) {
    float u = v * 2048.0f;
    if (!(u >= 0.0f) || u > 2048.0f) return 0;   // v<0, v>1, or NaN
    int k = (int)ceilf(u) - 1;
    return k < 0 ? 0 : k;
}

__device__ __forceinline__ float sigmoidf_(float x) { return 1.0f / (1.0f + expf(-x)); }

__device__ __forceinline__ u16 to_bf16(float x) {
    __hip_bfloat16 hb = __float2bfloat16(x);   // RTNE
    return *reinterpret_cast<u16*>(&hb);
}

// ---------------------------------------------------------------------------
// GATE-INTERLEAVED column packing: packed col c = u*4 + g  (u=c>>2, g=c&3).
// One 16-col MFMA ntile = 4 u's x 4 gates -> LSTM update is block-local,
// enabling 512 independent blocks (full chip) in the recurrent step.
// Fragment (l,i) of (nt,k0): bf16( W[(k0*32 + 8*(l>>4) + i)*8192 + gcol ] ),
// gcol = ((l&15)&3)*2048 + nt*4 + ((l&15)>>2). A-frags use the same k-map,
// so any in-fragment k-permutation cancels.
// PACK LDS uses a band-XOR swizzle: byte_off ^= ((row>>3)&3)<<5, so the
// 4 row-bands of a fragment read hit 4 distinct 32B windows -> conflict-free
// (round-16 layout was an 8-way conflict: every 256B row starts at bank 0).
// ---------------------------------------------------------------------------

// ---- K1 "front": blocks [0,512): per-ntile xz GEMM (all 8 t) + fused step0
// (self-sufficient: stages its own Wk slice + gathers A-frags from E);
// blocks [512,4608): Wr -> BW fragment pack (swizzled-LDS transpose).
__global__ __launch_bounds__(256) void k_front(
        const float* __restrict__ Wr, const float* __restrict__ Wk,
        const float* __restrict__ ip, const float* __restrict__ E,
        const float* __restrict__ bv, u16* __restrict__ BW,
        float* __restrict__ xz, float* __restrict__ H,
        float* __restrict__ c, u16* __restrict__ hA1) {
    __shared__ __align__(16) char smem[10240];
    int bx = blockIdx.x;
    int tid = threadIdx.x;

    if (bx < 512) {
        // ================= xz + step0 block =================
        u16 (*wk)[18] = (u16(*)[18])smem;            // 256 x 18 u16 (padded)
        float* zsh0 = (float*)(smem + 9216);         // 256 floats
        int nt = (bx & 7) * 64 + (bx >> 3);          // XCD swizzle
        int w = tid >> 6, l = tid & 63;

        // stage Wk slice: 256 rows x 16 packed cols (bf16), padded stride 18
        #pragma unroll
        for (int it = 0; it < 4; ++it) {
            int lin = it * 256 + tid;
            int k = lin >> 2;
            int g = lin & 3;
            float4 v = *(const float4*)&Wk[(size_t)k * 8192 + g * 2048 + nt * 4];
            wk[k][0 * 4 + g] = to_bf16(v.x);
            wk[k][1 * 4 + g] = to_bf16(v.y);
            wk[k][2 * 4 + g] = to_bf16(v.z);
            wk[k][3 * 4 + g] = to_bf16(v.w);
        }
        __syncthreads();

        int n = l & 15;
        float bias = bv[(n & 3) * 2048 + nt * 4 + (n >> 2)];

        // B-frags from padded LDS (conflict-free: 8g'+9i+lane/2 spans 32 banks)
        bf16x8 bw[8];
        #pragma unroll
        for (int s = 0; s < 8; ++s) {
            u16 o[8];
            #pragma unroll
            for (int i = 0; i < 8; ++i) o[i] = wk[s * 32 + 8 * (l >> 4) + i][n];
            bw[s] = *(bf16x8*)o;
        }

        // wave w handles t = 2w, 2w+1; A-frags gathered from E (same RTNE as XA)
        #pragma unroll
        for (int q = 0; q < 2; ++q) {
            int t = w * 2 + q;
            int tok = token_of(ip[n * LAT + t]);
            const float* er = E + (size_t)tok * EMB + 8 * (l >> 4);
            f32x4 acc = {bias, bias, bias, bias};
            #pragma unroll
            for (int s = 0; s < 8; ++s) {
                float4 e0 = *(const float4*)(er + s * 32);
                float4 e1 = *(const float4*)(er + s * 32 + 4);
                u16 o[8] = {to_bf16(e0.x), to_bf16(e0.y), to_bf16(e0.z), to_bf16(e0.w),
                            to_bf16(e1.x), to_bf16(e1.y), to_bf16(e1.z), to_bf16(e1.w)};
                acc = __builtin_amdgcn_mfma_f32_16x16x32_bf16(*(bf16x8*)o, bw[s], acc, 0, 0, 0);
            }
            #pragma unroll
            for (int i = 0; i < 4; ++i) {
                int b = 4 * (l >> 4) + i;   // D row = batch (m89-verified C/D layout)
                xz[(((size_t)t * 512 + nt) * 16 + b) * 16 + n] = acc[i];
                if (t == 0) zsh0[b * 16 + n] = acc[i];
            }
        }
        __syncthreads();

        // step0 update (h=c=0) for this block's 4 u's x 16 batches
        if (tid < 64) {
            int b = tid >> 2, ul = tid & 3;
            int myu = nt * 4 + ul;
            float z0 = zsh0[b * 16 + ul * 4 + 0];
            float z2 = zsh0[b * 16 + ul * 4 + 2];
            float z3 = zsh0[b * 16 + ul * 4 + 3];
            float cn = sigmoidf_(z0) * tanhf(z2);
            float hn = sigmoidf_(z3) * tanhf(cn);
            int tok = token_of(ip[b * LAT + 0]);
            float hw = tok != 0 ? hn : 0.0f;
            float cw = tok != 0 ? cn : 0.0f;
            c[b * 2048 + myu] = cw;
            H[b * 2048 + myu] = hw;
            u16 own = to_bf16(hw);
            int pair = __shfl_xor((int)own, 1);
            if (!(ul & 1)) {
                u32 val = (u32)own | ((u32)(u16)pair << 16);
                int k0 = myu >> 5, lg = (myu >> 3) & 3, i = myu & 7;
                *((u32*)hA1 + ((((k0 * 64) + lg * 16 + b) * 8 + i) >> 1)) = val;
            }
        }
    } else {
        // ================= Wr pack block =================
        int pb = bx - 512;
        int kc = pb >> 6, uc = pb & 63;

        // fill: thread (r = tid>>3, q8 = tid&7): float4 per gate (full lines),
        // two swizzled ds_write_b128 covering packed cols [q8*16, q8*16+15]
        {
            int r = tid >> 3, q8 = tid & 7;
            const float* base = Wr + (size_t)(kc * 32 + r) * 8192 + uc * 32 + q8 * 4;
            float4 v0 = *(const float4*)(base + 0 * 2048);
            float4 v1 = *(const float4*)(base + 1 * 2048);
            float4 v2 = *(const float4*)(base + 2 * 2048);
            float4 v3 = *(const float4*)(base + 3 * 2048);
            u16 lo[8] = {to_bf16(v0.x), to_bf16(v1.x), to_bf16(v2.x), to_bf16(v3.x),
                         to_bf16(v0.y), to_bf16(v1.y), to_bf16(v2.y), to_bf16(v3.y)};
            u16 hi[8] = {to_bf16(v0.z), to_bf16(v1.z), to_bf16(v2.z), to_bf16(v3.z),
                         to_bf16(v0.w), to_bf16(v1.w), to_bf16(v2.w), to_bf16(v3.w)};
            int key = ((r >> 3) & 3) << 5;
            char* lp = smem + r * 256;
            *(uint4*)(lp + ((q8 * 32) ^ key))      = *(uint4*)lo;
            *(uint4*)(lp + ((q8 * 32 + 16) ^ key)) = *(uint4*)hi;
        }
        __syncthreads();

        // assemble: 8 fragments (nt_l 0..7), 2 per thread, 16B coalesced stores
        int w = tid >> 6, l = tid & 63;
        #pragma unroll
        for (int q = 0; q < 2; ++q) {
            int nt_l = q * 4 + w;
            u16 o[8];
            #pragma unroll
            for (int i = 0; i < 8; ++i) {
                int rr = 8 * (l >> 4) + i;
                int key = ((rr >> 3) & 3) << 5;
                o[i] = *(const u16*)(smem + rr * 256 + ((nt_l * 32 + (l & 15) * 2) ^ key));
            }
            int nt = uc * 8 + nt_l;
            *(uint4*)(BW + ((size_t)(nt * 64 + kc) * 64 + l) * 8) = *(uint4*)o;
        }
    }
}

// ---- K2: fused step t. 512 blocks x 512 thr = 8 waves (K-eighths).
__global__ __launch_bounds__(512) void k_step(
        const u16* __restrict__ BW,
        const u16* __restrict__ hAin, u16* __restrict__ hAout,
        const float* __restrict__ xz, const float* __restrict__ ip,
        float* __restrict__ c, float* __restrict__ H, int t) {
    int j = blockIdx.x;
    int nt = (j & 7) * 64 + (j >> 3);
    int tid = threadIdx.x;
    int kq = tid >> 6, l = tid & 63;     // kq = K-eighth (0..7)
    __shared__ float zsh[8][256];

    const bf16x8* ap = (const bf16x8*)(hAin + ((size_t)(kq * 8) * 64 + l) * 8);
    const bf16x8* bp = (const bf16x8*)(BW + (((size_t)(nt * 64) + kq * 8) * 64 + l) * 8);
    bf16x8 ar[8], br[8];
    #pragma unroll
    for (int i = 0; i < 8; ++i) { ar[i] = ap[i * 64]; br[i] = bp[i * 64]; }

    f32x4 acc = {0.f, 0.f, 0.f, 0.f};
    #pragma unroll
    for (int s = 0; s < 8; ++s)
        acc = __builtin_amdgcn_mfma_f32_16x16x32_bf16(ar[s], br[s], acc, 0, 0, 0);

    #pragma unroll
    for (int i = 0; i < 4; ++i)
        zsh[kq][(4 * (l >> 4) + i) * 16 + (l & 15)] = acc[i];
    __syncthreads();

    if (tid < 64) {
        int b = tid >> 2, ul = tid & 3;
        int myu = nt * 4 + ul;
        float4 xv = *(const float4*)&xz[(((size_t)t * 512 + nt) * 16 + b) * 16 + ul * 4];
        float z[4] = {xv.x, xv.y, xv.z, xv.w};
        #pragma unroll
        for (int kk = 0; kk < 8; ++kk) {
            float4 zv = *(const float4*)&zsh[kk][b * 16 + ul * 4];
            z[0] += zv.x; z[1] += zv.y; z[2] += zv.z; z[3] += zv.w;
        }
        int idx = b * 2048 + myu;
        float co = c[idx];
        float ho = H[((size_t)(t - 1) * 16 + b) * 2048 + myu];
        float cn = sigmoidf_(z[1]) * co + sigmoidf_(z[0]) * tanhf(z[2]);
        float hn = sigmoidf_(z[3]) * tanhf(cn);
        int tok = token_of(ip[b * LAT + t]);
        float hw = tok != 0 ? hn : ho;
        float cw = tok != 0 ? cn : co;
        c[idx] = cw;
        H[((size_t)t * 16 + b) * 2048 + myu] = hw;
        u16 own = to_bf16(hw);
        int pair = __shfl_xor((int)own, 1);
        if (!(ul & 1)) {
            u32 val = (u32)own | ((u32)(u16)pair << 16);
            int k0 = myu >> 5, lg = (myu >> 3) & 3, i = myu & 7;
            *((u32*)hAout + ((((k0 * 64) + lg * 16 + b) * 8 + i) >> 1)) = val;
        }
    }
}

// ---- K3: softmax of all 128 recorded h rows -> d_out[b][t][:] ----
__global__ __launch_bounds__(256) void k_softmax(const float* __restrict__ H,
                                                 float* __restrict__ out) {
    int r = blockIdx.x;          // r = t*16 + b
    int t = r >> 4, b = r & 15;
    int tid = threadIdx.x;
    const float* hr = H + (size_t)r * VOCAB;
    float v[8];
    float m = -1e30f;
    #pragma unroll
    for (int i = 0; i < 8; ++i) { v[i] = hr[tid + i * 256]; m = fmaxf(m, v[i]); }

    __shared__ float redm[4], reds[4];
    int wid = tid >> 6, lane = tid & 63;
    #pragma unroll
    for (int off = 32; off; off >>= 1) m = fmaxf(m, __shfl_down(m, off));
    if (lane == 0) redm[wid] = m;
    __syncthreads();
    m = fmaxf(fmaxf(redm[0], redm[1]), fmaxf(redm[2], redm[3]));

    float e[8];
    float s = 0.0f;
    #pragma unroll
    for (int i = 0; i < 8; ++i) { e[i] = expf(v[i] - m); s += e[i]; }
    #pragma unroll
    for (int off = 32; off; off >>= 1) s += __shfl_down(s, off);
    if (lane == 0) reds[wid] = s;
    __syncthreads();
    s = reds[0] + reds[1] + reds[2] + reds[3];

    float* o = out + ((size_t)b * MAXLEN + t) * VOCAB;
    #pragma unroll
    for (int i = 0; i < 8; ++i) o[tid + i * 256] = e[i] / s;
}

extern "C" void kernel_launch(void* const* d_in, const int* in_sizes, int n_in,
                              void* d_out, int out_size, void* d_ws, size_t ws_size,
                              hipStream_t stream) {
    const float* ip = (const float*)d_in[0];   // (16,16)
    const float* E  = (const float*)d_in[1];   // (2048,256)
    const float* Wk = (const float*)d_in[2];   // (256,8192)
    const float* Wr = (const float*)d_in[3];   // (2048,8192)
    const float* bv = (const float*)d_in[4];   // (8192,)

    char* w = (char*)d_ws;
    float* xz  = (float*)w;  w += (size_t)8 * 512 * 16 * 16 * 4;       // 4 MB
    float* H   = (float*)w;  w += (size_t)262144 * 4;                  // 1 MB
    float* c   = (float*)w;  w += (size_t)32768 * 4;                   // 128 KB
    u16* hA0 = (u16*)w;      w += (size_t)32768 * 2;
    u16* hA1 = (u16*)w;      w += (size_t)32768 * 2;
    u16* BW  = (u16*)w;      w += (size_t)16777216 * 2;                // 32 MB

    k_front<<<4608, 256, 0, stream>>>(Wr, Wk, ip, E, bv, BW, xz, H, c, hA1);
    u16* hAbuf[2] = {hA0, hA1};
    for (int t = 1; t < MAXLEN; ++t)
        k_step<<<512, 512, 0, stream>>>(BW, hAbuf[t & 1], hAbuf[(t + 1) & 1],
                                        xz, ip, c, H, t);
    k_softmax<<<128, 256, 0, stream>>>(H, (float*)d_out);
}